// Round 3
// baseline (1067.063 us; speedup 1.0000x reference)
//
#include <hip/hip_runtime.h>
#include <math.h>

#define HID 128
#define G3  384
#define BATCH 256
#define SEQ 512
#define NB 16            // batch tile per block
#define NBLK (BATCH/NB)  // 16 blocks

typedef __bf16 bf16x8 __attribute__((ext_vector_type(8)));
typedef __bf16 bf16x4 __attribute__((ext_vector_type(4)));
typedef float  f32x4  __attribute__((ext_vector_type(4)));

#define LOG2E 1.44269504088896f

__device__ __forceinline__ float sigm(float x) {
    return __builtin_amdgcn_rcpf(1.f + __builtin_amdgcn_exp2f(-LOG2E * x));
}
__device__ __forceinline__ float tanh_fast(float x) {
    float e = __builtin_amdgcn_exp2f(-2.f * LOG2E * x);
    return __builtin_amdgcn_rcpf(1.f + e) * 2.f - 1.f;
}
__device__ __forceinline__ f32x4 mfma16(bf16x8 a, bf16x8 b, f32x4 c) {
    return __builtin_amdgcn_mfma_f32_16x16x32_bf16(a, b, c, 0, 0, 0);
}
__device__ __forceinline__ bf16x8 cvt8(float4 a, float4 b) {
    bf16x8 f;
    f[0] = (__bf16)a.x; f[1] = (__bf16)a.y; f[2] = (__bf16)a.z; f[3] = (__bf16)a.w;
    f[4] = (__bf16)b.x; f[5] = (__bf16)b.y; f[6] = (__bf16)b.z; f[7] = (__bf16)b.w;
    return f;
}

// ---------------------------------------------------------------------------
// Kernel 1: fold Linear into GRU input-hidden weights (unchanged).
// ---------------------------------------------------------------------------
__global__ void fold_kernel(const float* __restrict__ lin_W,
                            const float* __restrict__ lin_b,
                            const float* __restrict__ W_ih,
                            const float* __restrict__ b_ih,
                            float* __restrict__ Wc,
                            float* __restrict__ bcA) {
    const int g = blockIdx.x;
    const int d = threadIdx.x;
    float acc = 0.f;
    for (int e = 0; e < HID; ++e) acc += W_ih[g * HID + e] * lin_W[e * HID + d];
    Wc[g * HID + d] = acc;
    if (d == 0) {
        float b = 0.f;
        for (int e = 0; e < HID; ++e) b += W_ih[g * HID + e] * lin_b[e];
        bcA[g] = b + b_ih[g];
    }
}

// ---------------------------------------------------------------------------
// Kernel 2: MFMA GRU scan. 16 blocks x 512 threads (8 waves, 2 waves/SIMD).
// Wave w owns row-tile w (16 rows) of each gate. Weights (bf16 A-frags of
// W_hh and Wc) resident in registers: 24 frags = 96 VGPRs/wave.
// h double-buffered in XOR-swizzled LDS (one raw s_barrier per step, lgkmcnt
// drain only -- global x prefetch loads stay in flight across the barrier).
// x MFMA B-frags load straight from global into registers (no LDS staging).
// ---------------------------------------------------------------------------
__global__ __launch_bounds__(512, 2)
void gru_scan_mfma(const float* __restrict__ X,
                   const float* __restrict__ h0,
                   const float* __restrict__ W_hh,
                   const float* __restrict__ b_hh,
                   const float* __restrict__ Wc,
                   const float* __restrict__ bcA,
                   float* __restrict__ out) {
    const int t   = threadIdx.x;
    const int w   = t >> 6;     // 0..7: row-tile
    const int l   = t & 63;
    const int col = l & 15;     // batch col within tile
    const int lr  = l >> 4;     // 0..3
    const int bb  = blockIdx.x * NB;

    __shared__ __align__(16) unsigned char lds[8192];
    unsigned char* hb0 = lds;          // h buffer (even steps read this)
    unsigned char* hb1 = lds + 4096;   // h buffer (odd steps read this)

    auto SW = [](int b, int off) { return b * 256 + (off ^ ((b & 7) << 4)); };

    // ---- resident A-fragments: aW = W_hh, aC = Wc; [gate][ktile] --------
    bf16x8 aW[3][4], aC[3][4];
    #pragma unroll
    for (int g3 = 0; g3 < 3; ++g3)
        #pragma unroll
        for (int kt = 0; kt < 4; ++kt) {
            const int row = g3 * HID + w * 16 + col;
            const float* pw = W_hh + row * HID + kt * 32 + lr * 8;
            const float* pc = Wc   + row * HID + kt * 32 + lr * 8;
            aW[g3][kt] = cvt8(*(const float4*)pw, *(const float4*)(pw + 4));
            aC[g3][kt] = cvt8(*(const float4*)pc, *(const float4*)(pc + 4));
        }
    #pragma unroll
    for (int g3 = 0; g3 < 3; ++g3)
        #pragma unroll
        for (int kt = 0; kt < 4; ++kt) {
            asm volatile("" : "+v"(aW[g3][kt]));
            asm volatile("" : "+v"(aC[g3][kt]));
        }

    // ---- biases per lane (4 hidden rows: g = w*16 + lr*4 + q) -----------
    float br[4], bz[4], bnx[4], bnh[4];
    #pragma unroll
    for (int q = 0; q < 4; ++q) {
        const int g = w * 16 + lr * 4 + q;
        br[q]  = bcA[g] + b_hh[g];
        bz[q]  = bcA[HID + g] + b_hh[HID + g];
        bnx[q] = bcA[2 * HID + g];
        bnh[q] = b_hh[2 * HID + g];
    }

    // ---- h_old rows this lane owns (fp32, registers) --------------------
    f32x4 hold = *(const f32x4*)(h0 + (size_t)(bb + col) * HID + w * 16 + lr * 4);

    // ---- stage h0 into hb0 ----------------------------------------------
    if (t < 256) {
        const int sb = t >> 4, sk = (t & 15) * 8;
        const float* ph = h0 + (size_t)(bb + sb) * HID + sk;
        *(bf16x8*)(hb0 + SW(sb, sk * 2)) =
            cvt8(*(const float4*)ph, *(const float4*)(ph + 4));
    }

    // ---- initial x load (s=0) into registers ----------------------------
    float4 xA[8], xB[8];
    {
        const float* px = X + ((size_t)0 * BATCH + bb + col) * HID + lr * 8;
        #pragma unroll
        for (int kt = 0; kt < 4; ++kt) {
            xA[2 * kt]     = *(const float4*)(px + kt * 32);
            xA[2 * kt + 1] = *(const float4*)(px + kt * 32 + 4);
        }
    }

    asm volatile("s_waitcnt lgkmcnt(0)" ::: "memory");
    __builtin_amdgcn_s_barrier();

    const f32x4 vzero = {0.f, 0.f, 0.f, 0.f};

    auto STEP = [&](int s, unsigned char* bufR, unsigned char* bufW,
                    float4 (&xc)[8], float4 (&xn)[8]) {
        // issue next-step x loads first (max prefetch window, vmcnt stays
        // outstanding across the barrier -- no vmcnt(0) drain in this loop)
        {
            int sp = s + 1; if (sp > SEQ - 1) sp = SEQ - 1;
            const float* px = X + ((size_t)sp * BATCH + bb + col) * HID + lr * 8;
            #pragma unroll
            for (int kt = 0; kt < 4; ++kt) {
                xn[2 * kt]     = *(const float4*)(px + kt * 32);
                xn[2 * kt + 1] = *(const float4*)(px + kt * 32 + 4);
            }
        }
        // h B-fragments from LDS
        bf16x8 Bh[4];
        #pragma unroll
        for (int kt = 0; kt < 4; ++kt)
            Bh[kt] = *(const bf16x8*)(bufR + SW(col, kt * 64 + lr * 16));
        // current x to bf16 B-frags (register-only, runs in ds_read shadow)
        bf16x8 Bx[4];
        #pragma unroll
        for (int kt = 0; kt < 4; ++kt)
            Bx[kt] = cvt8(xc[2 * kt], xc[2 * kt + 1]);

        // MFMA: 24 per wave
        f32x4 ar = vzero, az = vzero, anh = vzero, anx = vzero;
        #pragma unroll
        for (int kt = 0; kt < 4; ++kt) {
            ar  = mfma16(aW[0][kt], Bh[kt], ar);
            ar  = mfma16(aC[0][kt], Bx[kt], ar);
            az  = mfma16(aW[1][kt], Bh[kt], az);
            az  = mfma16(aC[1][kt], Bx[kt], az);
            anh = mfma16(aW[2][kt], Bh[kt], anh);
            anx = mfma16(aC[2][kt], Bx[kt], anx);
        }

        // gate math (fp32, registers)
        f32x4 hnew;
        #pragma unroll
        for (int q = 0; q < 4; ++q) {
            float r = sigm(ar[q] + br[q]);
            float z = sigm(az[q] + bz[q]);
            float n = tanh_fast(anx[q] + bnx[q] + r * (anh[q] + bnh[q]));
            hnew[q] = n + z * (hold[q] - n);
        }
        hold = hnew;

        // h_new -> other LDS buffer (bf16)
        bf16x4 hv;
        hv[0] = (__bf16)hnew[0]; hv[1] = (__bf16)hnew[1];
        hv[2] = (__bf16)hnew[2]; hv[3] = (__bf16)hnew[3];
        *(bf16x4*)(bufW + SW(col, (w * 16 + lr * 4) * 2)) = hv;

        // output (fp32, global; store never waited on)
        float4 o; o.x = hnew[0]; o.y = hnew[1]; o.z = hnew[2]; o.w = hnew[3];
        *(float4*)(out + ((size_t)s * BATCH + bb + col) * HID + w * 16 + lr * 4) = o;

        // one barrier per step: LDS-visibility only (lgkmcnt), vmcnt flows
        asm volatile("s_waitcnt lgkmcnt(0)" ::: "memory");
        __builtin_amdgcn_s_barrier();
    };

    for (int s0 = 0; s0 < SEQ; s0 += 2) {
        STEP(s0,     hb0, hb1, xA, xB);
        STEP(s0 + 1, hb1, hb0, xB, xA);
    }
}

// ---------------------------------------------------------------------------
extern "C" void kernel_launch(void* const* d_in, const int* in_sizes, int n_in,
                              void* d_out, int out_size, void* d_ws, size_t ws_size,
                              hipStream_t stream) {
    const float* X     = (const float*)d_in[0];
    const float* h0    = (const float*)d_in[1];
    const float* lin_W = (const float*)d_in[2];
    const float* lin_b = (const float*)d_in[3];
    const float* W_ih  = (const float*)d_in[4];
    const float* W_hh  = (const float*)d_in[5];
    const float* b_ih  = (const float*)d_in[6];
    const float* b_hh  = (const float*)d_in[7];
    float* out = (float*)d_out;

    float* Wc  = (float*)d_ws;
    float* bcA = Wc + G3 * HID;

    fold_kernel<<<G3, HID, 0, stream>>>(lin_W, lin_b, W_ih, b_ih, Wc, bcA);
    gru_scan_mfma<<<NBLK, 512, 0, stream>>>(X, h0, W_hh, b_hh, Wc, bcA, out);
}

// Round 5
// 708.244 us; speedup vs baseline: 1.5066x; 1.5066x over previous
//
#include <hip/hip_runtime.h>
#include <math.h>

#define HID 128
#define G3  384
#define BATCH 256
#define SEQ 512
#define NB 16            // batch tile per block
#define NBLK (BATCH/NB)  // 16 blocks

typedef __bf16 bf16x8 __attribute__((ext_vector_type(8)));
typedef __bf16 bf16x4 __attribute__((ext_vector_type(4)));
typedef float  f32x4  __attribute__((ext_vector_type(4)));

#define LOG2E 1.44269504088896f

__device__ __forceinline__ float sigm(float x) {
    return __builtin_amdgcn_rcpf(1.f + __builtin_amdgcn_exp2f(-LOG2E * x));
}
__device__ __forceinline__ float tanh_fast(float x) {
    float e = __builtin_amdgcn_exp2f(-2.f * LOG2E * x);
    return __builtin_amdgcn_rcpf(1.f + e) * 2.f - 1.f;
}
__device__ __forceinline__ f32x4 mfma16(bf16x8 a, bf16x8 b, f32x4 c) {
    return __builtin_amdgcn_mfma_f32_16x16x32_bf16(a, b, c, 0, 0, 0);
}
__device__ __forceinline__ bf16x8 cvt8(float4 a, float4 b) {
    bf16x8 f;
    f[0] = (__bf16)a.x; f[1] = (__bf16)a.y; f[2] = (__bf16)a.z; f[3] = (__bf16)a.w;
    f[4] = (__bf16)b.x; f[5] = (__bf16)b.y; f[6] = (__bf16)b.z; f[7] = (__bf16)b.w;
    return f;
}

// ---------------------------------------------------------------------------
// Kernel 1: fold Linear into GRU input-hidden weights (unchanged).
// ---------------------------------------------------------------------------
__global__ void fold_kernel(const float* __restrict__ lin_W,
                            const float* __restrict__ lin_b,
                            const float* __restrict__ W_ih,
                            const float* __restrict__ b_ih,
                            float* __restrict__ Wc,
                            float* __restrict__ bcA) {
    const int g = blockIdx.x;
    const int d = threadIdx.x;
    float acc = 0.f;
    for (int e = 0; e < HID; ++e) acc += W_ih[g * HID + e] * lin_W[e * HID + d];
    Wc[g * HID + d] = acc;
    if (d == 0) {
        float b = 0.f;
        for (int e = 0; e < HID; ++e) b += W_ih[g * HID + e] * lin_b[e];
        bcA[g] = b + b_ih[g];
    }
}

// ---------------------------------------------------------------------------
// Kernel 2: MFMA GRU scan. 16 blocks x 256 threads (4 waves) -- round-2
// structure (weights resident as bf16 A-frags, h/x in XOR-swizzled LDS)
// with barrier surgery: h AND x double-buffered so there is exactly ONE
// raw s_barrier per step, drained with lgkmcnt(0) only. No vmcnt(0) is
// ever issued in the loop: out-stores and the x global prefetch stay in
// flight across barriers. Prefetched x regs are pinned (input-only asm)
// at end-of-step to stop LLVM sinking the readonly loads to their use.
// ---------------------------------------------------------------------------
__global__ __launch_bounds__(256, 1)
void gru_scan_mfma(const float* __restrict__ X,
                   const float* __restrict__ h0,
                   const float* __restrict__ W_hh,
                   const float* __restrict__ b_hh,
                   const float* __restrict__ Wc,
                   const float* __restrict__ bcA,
                   float* __restrict__ out) {
    const int t   = threadIdx.x;
    const int w   = t >> 6;
    const int l   = t & 63;
    const int col = l & 15;   // batch within tile (MFMA n / C col)
    const int lr  = l >> 4;   // 0..3
    const int bb  = blockIdx.x * NB;

    __shared__ __align__(16) unsigned char lds[16384];
    unsigned char* hA = lds;            // h buffer, even-step read
    unsigned char* hB = lds + 4096;     // h buffer, odd-step read
    unsigned char* xA = lds + 8192;     // x buffer, even-step read
    unsigned char* xB = lds + 12288;    // x buffer, odd-step read

    auto SW = [](int b, int off) { return b * 256 + (off ^ ((b & 7) << 4)); };

    const int T[2] = {w, w + 4};

    // ---- resident A-fragments: aW = W_hh, aC = Wc; [tile][gate][ktile] ----
    bf16x8 aW[2][3][4], aC[2][3][4];
    #pragma unroll
    for (int i = 0; i < 2; ++i)
        #pragma unroll
        for (int g3 = 0; g3 < 3; ++g3)
            #pragma unroll
            for (int kt = 0; kt < 4; ++kt) {
                const int row = g3 * HID + T[i] * 16 + col;
                const float* pw = W_hh + row * HID + kt * 32 + lr * 8;
                const float* pc = Wc   + row * HID + kt * 32 + lr * 8;
                aW[i][g3][kt] = cvt8(*(const float4*)pw, *(const float4*)(pw + 4));
                aC[i][g3][kt] = cvt8(*(const float4*)pc, *(const float4*)(pc + 4));
            }
    #pragma unroll
    for (int i = 0; i < 2; ++i)
        #pragma unroll
        for (int g3 = 0; g3 < 3; ++g3)
            #pragma unroll
            for (int kt = 0; kt < 4; ++kt) {
                asm volatile("" : "+v"(aW[i][g3][kt]));
                asm volatile("" : "+v"(aC[i][g3][kt]));
            }

    // ---- biases per lane ------------------------------------------------
    float br[2][4], bz[2][4], bnx[2][4], bnh[2][4];
    #pragma unroll
    for (int i = 0; i < 2; ++i)
        #pragma unroll
        for (int q = 0; q < 4; ++q) {
            const int g = T[i] * 16 + lr * 4 + q;
            br[i][q]  = bcA[g] + b_hh[g];
            bz[i][q]  = bcA[HID + g] + b_hh[HID + g];
            bnx[i][q] = bcA[2 * HID + g];
            bnh[i][q] = b_hh[2 * HID + g];
        }

    // ---- h_old in registers ---------------------------------------------
    f32x4 hold[2];
    #pragma unroll
    for (int i = 0; i < 2; ++i)
        hold[i] = *(const f32x4*)(h0 + (size_t)(bb + col) * HID + T[i] * 16 + lr * 4);

    // ---- prime: h0 -> hA, x[0] -> xA, x[1] -> regs ----------------------
    const int sb = t >> 4, sk = (t & 15) * 8;  // staging mapping (256 thr)
    float4 xp0, xp1, xq0, xq1;                 // ping-pong prefetch regs
    {
        const float* ph = h0 + (size_t)(bb + sb) * HID + sk;
        *(bf16x8*)(hA + SW(sb, sk * 2)) =
            cvt8(*(const float4*)ph, *(const float4*)(ph + 4));
        const float* px = X + ((size_t)0 * BATCH + bb + sb) * HID + sk;
        *(bf16x8*)(xA + SW(sb, sk * 2)) =
            cvt8(*(const float4*)px, *(const float4*)(px + 4));
        const float* p1 = X + ((size_t)1 * BATCH + bb + sb) * HID + sk;
        xp0 = *(const float4*)p1; xp1 = *(const float4*)(p1 + 4);
    }
    asm volatile("s_waitcnt lgkmcnt(0)" ::: "memory");
    __builtin_amdgcn_s_barrier();

    const f32x4 vzero = {0.f, 0.f, 0.f, 0.f};

    auto STEP = [&](int s, unsigned char* hR, unsigned char* hW,
                    unsigned char* xR, unsigned char* xW,
                    float4& xc0, float4& xc1, float4& xn0, float4& xn1) {
        // 1. stage x[s+1] (regs loaded last step) into the write buffer.
        //    The implicit vmcnt wait here targets a load issued a full step
        //    ago -- effectively free.
        *(bf16x8*)(xW + SW(sb, sk * 2)) = cvt8(xc0, xc1);

        // 2. issue x[s+2] global load (consumed at the top of step s+2)
        {
            int sp = s + 2; if (sp > SEQ - 1) sp = SEQ - 1;
            const float* px = X + ((size_t)sp * BATCH + bb + sb) * HID + sk;
            xn0 = *(const float4*)px; xn1 = *(const float4*)(px + 4);
        }

        // 3. B-fragments from LDS
        bf16x8 Bh[4], Bx[4];
        #pragma unroll
        for (int kt = 0; kt < 4; ++kt) {
            Bh[kt] = *(const bf16x8*)(hR + SW(col, kt * 64 + lr * 16));
            Bx[kt] = *(const bf16x8*)(xR + SW(col, kt * 64 + lr * 16));
        }

        // 4. MFMA: 48 per wave
        f32x4 ar[2], az[2], anh[2], anx[2];
        #pragma unroll
        for (int i = 0; i < 2; ++i) { ar[i] = vzero; az[i] = vzero; anh[i] = vzero; anx[i] = vzero; }
        #pragma unroll
        for (int i = 0; i < 2; ++i)
            #pragma unroll
            for (int kt = 0; kt < 4; ++kt) {
                ar[i]  = mfma16(aW[i][0][kt], Bh[kt], ar[i]);
                ar[i]  = mfma16(aC[i][0][kt], Bx[kt], ar[i]);
                az[i]  = mfma16(aW[i][1][kt], Bh[kt], az[i]);
                az[i]  = mfma16(aC[i][1][kt], Bx[kt], az[i]);
                anh[i] = mfma16(aW[i][2][kt], Bh[kt], anh[i]);
                anx[i] = mfma16(aC[i][2][kt], Bx[kt], anx[i]);
            }

        // 5. gate math + h_new writeback (h -> hW, out -> global)
        #pragma unroll
        for (int i = 0; i < 2; ++i) {
            f32x4 hnew;
            #pragma unroll
            for (int q = 0; q < 4; ++q) {
                float r = sigm(ar[i][q] + br[i][q]);
                float z = sigm(az[i][q] + bz[i][q]);
                float n = tanh_fast(anx[i][q] + bnx[i][q] +
                                    r * (anh[i][q] + bnh[i][q]));
                hnew[q] = n + z * (hold[i][q] - n);
            }
            hold[i] = hnew;
            bf16x4 hv;
            hv[0] = (__bf16)hnew[0]; hv[1] = (__bf16)hnew[1];
            hv[2] = (__bf16)hnew[2]; hv[3] = (__bf16)hnew[3];
            *(bf16x4*)(hW + SW(col, (T[i] * 16 + lr * 4) * 2)) = hv;
            float4 o; o.x = hnew[0]; o.y = hnew[1]; o.z = hnew[2]; o.w = hnew[3];
            *(float4*)(out + ((size_t)s * BATCH + bb + col) * HID + T[i] * 16 + lr * 4) = o;
        }

        // 6. pin prefetched x regs (input-only asm: forces the loads to
        //    have materialized here, i.e. before the barrier; no tie).
        asm volatile("" :: "v"(xn0.x), "v"(xn0.y), "v"(xn0.z), "v"(xn0.w),
                           "v"(xn1.x), "v"(xn1.y), "v"(xn1.z), "v"(xn1.w));

        // 7. single barrier: LDS visibility only; vmcnt flows across.
        asm volatile("s_waitcnt lgkmcnt(0)" ::: "memory");
        __builtin_amdgcn_s_barrier();
    };

    for (int s0 = 0; s0 < SEQ; s0 += 2) {
        STEP(s0,     hA, hB, xA, xB, xp0, xp1, xq0, xq1);
        STEP(s0 + 1, hB, hA, xB, xA, xq0, xq1, xp0, xp1);
    }
}

// ---------------------------------------------------------------------------
extern "C" void kernel_launch(void* const* d_in, const int* in_sizes, int n_in,
                              void* d_out, int out_size, void* d_ws, size_t ws_size,
                              hipStream_t stream) {
    const float* X     = (const float*)d_in[0];
    const float* h0    = (const float*)d_in[1];
    const float* lin_W = (const float*)d_in[2];
    const float* lin_b = (const float*)d_in[3];
    const float* W_ih  = (const float*)d_in[4];
    const float* W_hh  = (const float*)d_in[5];
    const float* b_ih  = (const float*)d_in[6];
    const float* b_hh  = (const float*)d_in[7];
    float* out = (float*)d_out;

    float* Wc  = (float*)d_ws;
    float* bcA = Wc + G3 * HID;

    fold_kernel<<<G3, HID, 0, stream>>>(lin_W, lin_b, W_ih, b_ih, Wc, bcA);
    gru_scan_mfma<<<NBLK, 256, 0, stream>>>(X, h0, W_hh, b_hh, Wc, bcA, out);
}

// Round 6
// 439.090 us; speedup vs baseline: 2.4302x; 1.6130x over previous
//
#include <hip/hip_runtime.h>
#include <math.h>

#define HID 128
#define G3  384
#define BATCH 256
#define SEQ 512
#define NB 16            // batch tile per block
#define NBLK (BATCH/NB)  // 16 blocks

typedef __bf16 bf16x8 __attribute__((ext_vector_type(8)));
typedef __bf16 bf16x4 __attribute__((ext_vector_type(4)));
typedef float  f32x4  __attribute__((ext_vector_type(4)));

#define LOG2E 1.44269504088896f

__device__ __forceinline__ float sigm(float x) {
    return __builtin_amdgcn_rcpf(1.f + __builtin_amdgcn_exp2f(-LOG2E * x));
}
__device__ __forceinline__ float tanh_fast(float x) {
    float e = __builtin_amdgcn_exp2f(-2.f * LOG2E * x);
    return __builtin_amdgcn_rcpf(1.f + e) * 2.f - 1.f;
}
__device__ __forceinline__ f32x4 mfma16(bf16x8 a, bf16x8 b, f32x4 c) {
    return __builtin_amdgcn_mfma_f32_16x16x32_bf16(a, b, c, 0, 0, 0);
}
__device__ __forceinline__ bf16x8 cvt8(float4 a, float4 b) {
    bf16x8 f;
    f[0] = (__bf16)a.x; f[1] = (__bf16)a.y; f[2] = (__bf16)a.z; f[3] = (__bf16)a.w;
    f[4] = (__bf16)b.x; f[5] = (__bf16)b.y; f[6] = (__bf16)b.z; f[7] = (__bf16)b.w;
    return f;
}
__device__ __forceinline__ bf16x4 cvt4(float4 a) {
    bf16x4 f;
    f[0] = (__bf16)a.x; f[1] = (__bf16)a.y; f[2] = (__bf16)a.z; f[3] = (__bf16)a.w;
    return f;
}

// ---------------------------------------------------------------------------
// Kernel 1: fold Linear into GRU input-hidden weights (unchanged).
// ---------------------------------------------------------------------------
__global__ void fold_kernel(const float* __restrict__ lin_W,
                            const float* __restrict__ lin_b,
                            const float* __restrict__ W_ih,
                            const float* __restrict__ b_ih,
                            float* __restrict__ Wc,
                            float* __restrict__ bcA) {
    const int g = blockIdx.x;
    const int d = threadIdx.x;
    float acc = 0.f;
    for (int e = 0; e < HID; ++e) acc += W_ih[g * HID + e] * lin_W[e * HID + d];
    Wc[g * HID + d] = acc;
    if (d == 0) {
        float b = 0.f;
        for (int e = 0; e < HID; ++e) b += W_ih[g * HID + e] * lin_b[e];
        bcA[g] = b + b_ih[g];
    }
}

// ---------------------------------------------------------------------------
// Kernel 2: MFMA GRU scan -- round-2 structure (two __syncthreads per step,
// x double-buffered in LDS, x prefetch via regs) with ONE change isolated:
// 8 waves (512 thr, 2 waves/SIMD) instead of 4, each wave owning a single
// 16-row tile per gate (24 MFMA/wave). TLP hides ds_read/MFMA/VALU latency
// that was fully exposed at 1 wave/SIMD.
// ---------------------------------------------------------------------------
__global__ __launch_bounds__(512, 2)
void gru_scan_mfma(const float* __restrict__ X,
                   const float* __restrict__ h0,
                   const float* __restrict__ W_hh,
                   const float* __restrict__ b_hh,
                   const float* __restrict__ Wc,
                   const float* __restrict__ bcA,
                   float* __restrict__ out) {
    const int t   = threadIdx.x;
    const int w   = t >> 6;     // 0..7: row tile (16 rows of each gate)
    const int l   = t & 63;
    const int col = l & 15;     // batch within tile (MFMA n / C col)
    const int lr  = l >> 4;     // 0..3
    const int bb  = blockIdx.x * NB;

    __shared__ __align__(16) unsigned char lds[12288];
    unsigned char* hbuf  = lds;           // 4 KB: h [16][128] bf16 swizzled
    unsigned char* xbuf0 = lds + 4096;    // 4 KB: x double-buffer 0
    unsigned char* xbuf1 = lds + 8192;    // 4 KB: x double-buffer 1

    auto SW = [](int b, int off) { return b * 256 + (off ^ ((b & 7) << 4)); };

    // ---- resident A-fragments: aW = W_hh, aC = Wc; [gate][ktile] --------
    bf16x8 aW[3][4], aC[3][4];
    #pragma unroll
    for (int g3 = 0; g3 < 3; ++g3)
        #pragma unroll
        for (int kt = 0; kt < 4; ++kt) {
            const int row = g3 * HID + w * 16 + col;
            const float* pw = W_hh + row * HID + kt * 32 + lr * 8;
            const float* pc = Wc   + row * HID + kt * 32 + lr * 8;
            aW[g3][kt] = cvt8(*(const float4*)pw, *(const float4*)(pw + 4));
            aC[g3][kt] = cvt8(*(const float4*)pc, *(const float4*)(pc + 4));
        }
    #pragma unroll
    for (int g3 = 0; g3 < 3; ++g3)
        #pragma unroll
        for (int kt = 0; kt < 4; ++kt) {
            asm volatile("" : "+v"(aW[g3][kt]));
            asm volatile("" : "+v"(aC[g3][kt]));
        }

    // ---- biases per lane (4 rows: g = w*16 + lr*4 + q) ------------------
    float br[4], bz[4], bnx[4], bnh[4];
    #pragma unroll
    for (int q = 0; q < 4; ++q) {
        const int g = w * 16 + lr * 4 + q;
        br[q]  = bcA[g] + b_hh[g];
        bz[q]  = bcA[HID + g] + b_hh[HID + g];
        bnx[q] = bcA[2 * HID + g];
        bnh[q] = b_hh[2 * HID + g];
    }

    // ---- h_old rows this lane owns (fp32, registers) --------------------
    f32x4 hold = *(const f32x4*)(h0 + (size_t)(bb + col) * HID + w * 16 + lr * 4);

    // ---- staging mapping: all 512 threads, 16B global read / 8B LDS write
    const int sb = t >> 5;            // 0..15 batch row
    const int sk = (t & 31) * 4;      // 0..124 k offset (floats)

    // ---- prime: h0 -> hbuf (256 thr), x[0] -> xbuf0, x[1] -> regs -------
    float4 xp, xq;                    // ping-pong prefetch regs
    if (t < 256) {
        const int hb = t >> 4, hk = (t & 15) * 8;
        const float* ph = h0 + (size_t)(bb + hb) * HID + hk;
        *(bf16x8*)(hbuf + SW(hb, hk * 2)) =
            cvt8(*(const float4*)ph, *(const float4*)(ph + 4));
    }
    {
        const float* px = X + ((size_t)0 * BATCH + bb + sb) * HID + sk;
        *(bf16x4*)(xbuf0 + SW(sb, sk * 2)) = cvt4(*(const float4*)px);
        const float* p1 = X + ((size_t)1 * BATCH + bb + sb) * HID + sk;
        xp = *(const float4*)p1;
    }
    __syncthreads();

    const f32x4 vzero = {0.f, 0.f, 0.f, 0.f};

    auto STEP = [&](int s, unsigned char* xcur, unsigned char* xnxt,
                    float4& xc, float4& xn) {
        // B-fragments from LDS (shared across all row tiles)
        bf16x8 Bh[4], Bx[4];
        #pragma unroll
        for (int kt = 0; kt < 4; ++kt) {
            Bh[kt] = *(const bf16x8*)(hbuf + SW(col, kt * 64 + lr * 16));
            Bx[kt] = *(const bf16x8*)(xcur + SW(col, kt * 64 + lr * 16));
        }
        // prefetch x[s+2] (clamped; redundant tail loads harmless)
        {
            int sp = s + 2; if (sp > SEQ - 1) sp = SEQ - 1;
            const float* px = X + ((size_t)sp * BATCH + bb + sb) * HID + sk;
            xn = *(const float4*)px;
        }
        // MFMA: 24 per wave
        f32x4 ar = vzero, az = vzero, anh = vzero, anx = vzero;
        #pragma unroll
        for (int kt = 0; kt < 4; ++kt) {
            ar  = mfma16(aW[0][kt], Bh[kt], ar);
            ar  = mfma16(aC[0][kt], Bx[kt], ar);
            az  = mfma16(aW[1][kt], Bh[kt], az);
            az  = mfma16(aC[1][kt], Bx[kt], az);
            anh = mfma16(aW[2][kt], Bh[kt], anh);
            anx = mfma16(aC[2][kt], Bx[kt], anx);
        }
        __syncthreads();   // all LDS reads of h/x done; safe to overwrite

        // stage x[s+1] (loaded last step) into the other x buffer
        *(bf16x4*)(xnxt + SW(sb, sk * 2)) = cvt4(xc);

        // gate math (fp32, registers) + h_new writeback
        f32x4 hnew;
        #pragma unroll
        for (int q = 0; q < 4; ++q) {
            float r = sigm(ar[q] + br[q]);
            float z = sigm(az[q] + bz[q]);
            float n = tanh_fast(anx[q] + bnx[q] + r * (anh[q] + bnh[q]));
            hnew[q] = n + z * (hold[q] - n);
        }
        hold = hnew;
        *(bf16x4*)(hbuf + SW(col, (w * 16 + lr * 4) * 2)) = cvt4(*(float4*)&hnew);
        float4 o; o.x = hnew[0]; o.y = hnew[1]; o.z = hnew[2]; o.w = hnew[3];
        *(float4*)(out + ((size_t)s * BATCH + bb + col) * HID + w * 16 + lr * 4) = o;

        __syncthreads();   // h/x writes visible before next step's reads
    };

    for (int s0 = 0; s0 < SEQ; s0 += 2) {
        STEP(s0,     xbuf0, xbuf1, xp, xq);
        STEP(s0 + 1, xbuf1, xbuf0, xq, xp);
    }
}

// ---------------------------------------------------------------------------
extern "C" void kernel_launch(void* const* d_in, const int* in_sizes, int n_in,
                              void* d_out, int out_size, void* d_ws, size_t ws_size,
                              hipStream_t stream) {
    const float* X     = (const float*)d_in[0];
    const float* h0    = (const float*)d_in[1];
    const float* lin_W = (const float*)d_in[2];
    const float* lin_b = (const float*)d_in[3];
    const float* W_ih  = (const float*)d_in[4];
    const float* W_hh  = (const float*)d_in[5];
    const float* b_ih  = (const float*)d_in[6];
    const float* b_hh  = (const float*)d_in[7];
    float* out = (float*)d_out;

    float* Wc  = (float*)d_ws;
    float* bcA = Wc + G3 * HID;

    fold_kernel<<<G3, HID, 0, stream>>>(lin_W, lin_b, W_ih, b_ih, Wc, bcA);
    gru_scan_mfma<<<NBLK, 512, 0, stream>>>(X, h0, W_hh, b_hh, Wc, bcA, out);
}